// Round 10
// baseline (47.296 us; speedup 1.0000x reference)
//
#include <hip/hip_runtime.h>
#include <hip/hip_bf16.h>
#include <math.h>

#define NROW 256
#define DIM  65536
#define LSTR 40             // LDS row stride in ushorts (32 + 8 pad)
#define PSP2 32832          // partial stride in ushorts (32768 + 64 pad)

typedef __attribute__((ext_vector_type(8))) short short8;
typedef __attribute__((ext_vector_type(4))) float f32x4;
typedef unsigned int       u32t;
typedef unsigned long long u64t;

__device__ __forceinline__ float bf2f(ushort h) {
    u32t u = ((u32t)h) << 16;
    return __builtin_bit_cast(float, u);
}
// packed fp32x2 -> bf16x2 (v_cvt_pk_bf16_f32, RNE)
__device__ __forceinline__ u32t pk2(float lo, float hi) {
    __hip_bfloat162 h = __float22bfloat162_rn(make_float2(lo, hi));
    u32t r; __builtin_memcpy(&r, &h, 4); return r;
}

// native-layout index of G[i][j] within the (mh, q) partial layout
__device__ __forceinline__ int gpos2(int i, int j) {
    const int mh  = i >> 7, il = i & 127;
    const int wid  = ((il >> 6) << 2) | (j >> 6);
    const int lane = (((il >> 2) & 3) << 4) | (j & 15);
    const int q = ((wid << 6) | lane) * 64
                + (((((il >> 4) & 3) << 2) | ((j >> 4) & 3)) << 2) + (il & 3);
    return mh * 32768 + q;
}

// ---------------------------------------------------------------------------
// Split-K x split-M MFMA GEMM: 512 blocks = 256 K-slices (s) x 2 row-halves
// (mh). Each block: output 128x256 over K=256, staged in 8 chunks of k=32
// (double-buffered 40KB LDS). acc=64 regs/thread, LDS 80KB/CU -> TWO blocks
// truly co-resident per CU: one block's global loads stream while the buddy
// computes/stores; 64KB epilogues overlap. blockIdx swizzle puts buddy pairs
// (same s, mh=0/1) on the SAME XCD (b, b+8) so the shared 256-row tile's
// second read is an L2 hit -> E costs ~one HBM pass.
// ---------------------------------------------------------------------------
__global__ __launch_bounds__(512, 4) void gemm_k(const float* __restrict__ E,
                                                 ushort* __restrict__ part) {
    const int b   = blockIdx.x;
    const int x   = b & 7;              // XCD slot
    const int mh  = (b >> 3) & 1;       // row half
    const int s   = x * 32 + (b >> 4);  // K-slice 0..255

    const int tid  = threadIdx.x;
    const int lane = tid & 63;
    const int wid  = tid >> 6;
    const int wr   = wid >> 2;          // 0..1 -> 64-row band within the half
    const int wc   = wid & 3;           // 0..3 -> 64-col band
    const int r15  = lane & 15;
    const int kgi  = lane >> 4;         // 0..3 -> 8-k slice within k=32

    __shared__ ushort es[2][NROW][LSTR];   // 40,960 B -> 2 blocks/CU

    const int row  = tid >> 1;          // staging row (2 threads/row)
    const int half = tid & 1;           // 64B half of the 128B row segment
    const size_t kbase = (size_t)s * 256;

    f32x4 acc[4][4];
    #pragma unroll
    for (int m = 0; m < 4; ++m)
        #pragma unroll
        for (int n = 0; n < 4; ++n) acc[m][n] = (f32x4){0.f, 0.f, 0.f, 0.f};

    auto LOADC = [&](int c, float4* v) {
        const float* p = E + ((size_t)row << 16) + kbase + c * 32 + half * 16;
        #pragma unroll
        for (int u = 0; u < 4; ++u) v[u] = *(const float4*)(p + u * 4);
    };
    auto WRITEC = [&](int buf, const float4* v) {
        #pragma unroll
        for (int u = 0; u < 4; ++u) {
            uint2 wv;
            wv.x = pk2(v[u].x, v[u].y);
            wv.y = pk2(v[u].z, v[u].w);
            *(uint2*)&es[buf][row][half * 16 + u * 4] = wv;
        }
    };

    float4 v0[4];
    LOADC(0, v0);
    WRITEC(0, v0);

    #pragma unroll
    for (int c = 0; c < 8; ++c) {
        __syncthreads();                // buf (c&1) staged; reads of other done
        float4 vn[4];
        if (c < 7) LOADC(c + 1, vn);    // issue next chunk's loads early
        const int ko = kgi * 8;
        short8 af[4], bfr[4];
        #pragma unroll
        for (int m = 0; m < 4; ++m)
            af[m] = *(const short8*)&es[c & 1][mh * 128 + wr * 64 + m * 16 + r15][ko];
        #pragma unroll
        for (int n = 0; n < 4; ++n)
            bfr[n] = *(const short8*)&es[c & 1][wc * 64 + n * 16 + r15][ko];
        #pragma unroll
        for (int m = 0; m < 4; ++m)
            #pragma unroll
            for (int n = 0; n < 4; ++n)
                acc[m][n] = __builtin_amdgcn_mfma_f32_16x16x32_bf16(
                    af[m], bfr[n], acc[m][n], 0, 0, 0);
        if (c < 7) WRITEC((c + 1) & 1, vn);   // waits vmcnt, fills other buf
    }

    // epilogue: 64 accs -> bf16, contiguous per-thread (coalesced 16B stores)
    ushort* pp = part + (size_t)(s * 2 + mh) * PSP2 + (size_t)tid * 64;
    #pragma unroll
    for (int m = 0; m < 4; ++m)
        #pragma unroll
        for (int n = 0; n < 4; n += 2) {
            uint4 q;
            q.x = pk2(acc[m][n][0],     acc[m][n][1]);
            q.y = pk2(acc[m][n][2],     acc[m][n][3]);
            q.z = pk2(acc[m][n + 1][0], acc[m][n + 1][1]);
            q.w = pk2(acc[m][n + 1][2], acc[m][n + 1][3]);
            *(uint4*)(pp + ((m << 2) | n) * 4) = q;
        }
}

// ---------------------------------------------------------------------------
// Partial reduction, 512 blocks: block (h, w) sums s-half h over a 256-pos
// window of output half mh=w>>7, 32 loads batched in flight. Writes
// Gh[h][w*256 + t]. Fixed tree: u-ascending, sg 0..3, then h0+h1 (row_loss).
// Also zeroes the fixed-point accumulator for row_loss (stream-ordered).
// ---------------------------------------------------------------------------
__global__ __launch_bounds__(256) void reduce_k(const ushort* __restrict__ part,
                                                float* __restrict__ Gh,
                                                u64t* __restrict__ acc,
                                                u32t* __restrict__ cnt) {
    if (blockIdx.x == 0 && threadIdx.x == 0) { *acc = 0ull; *cnt = 0u; }

    const int w  = blockIdx.x & 255;    // position window
    const int h  = blockIdx.x >> 8;     // s half
    const int mh = w >> 7;              // output row-half
    const int q0 = (w & 127) * 256;
    const int t = threadIdx.x, l = t & 63, sg = t >> 6;

    // s = h*128 + sg + 4u  ->  partial p = s*2 + mh
    const ushort* base = part + (size_t)((h * 128 + sg) * 2 + mh) * PSP2
                              + q0 + l * 4;

    uint2 r[32];
    #pragma unroll
    for (int u = 0; u < 32; ++u)
        r[u] = *(const uint2*)(base + (size_t)(8 * u) * PSP2);

    float a0 = 0.f, a1 = 0.f, a2 = 0.f, a3 = 0.f;
    #pragma unroll
    for (int u = 0; u < 32; ++u) {
        a0 += bf2f((ushort)(r[u].x & 0xffffu));
        a1 += bf2f((ushort)(r[u].x >> 16));
        a2 += bf2f((ushort)(r[u].y & 0xffffu));
        a3 += bf2f((ushort)(r[u].y >> 16));
    }
    __shared__ float sh[4][256];
    sh[sg][l * 4 + 0] = a0; sh[sg][l * 4 + 1] = a1;
    sh[sg][l * 4 + 2] = a2; sh[sg][l * 4 + 3] = a3;
    __syncthreads();
    Gh[(size_t)h * 65536 + w * 256 + t] =
        (sh[0][t] + sh[1][t]) + (sh[2][t] + sh[3][t]);
}

// ---------------------------------------------------------------------------
// Fused per-row softmax loss + deterministic final sum (fixed-point atomic,
// order-independent). PSD term provably 0 (AM-GM; clip at 0), omitted.
// ---------------------------------------------------------------------------
__global__ __launch_bounds__(256) void row_loss_k(const float* __restrict__ Gh,
                                                  const int* __restrict__ labels,
                                                  u64t* __restrict__ acc,
                                                  u32t* __restrict__ cnt,
                                                  float* __restrict__ out) {
    const int i = blockIdx.x;
    const int j = threadIdx.x;

    const int pii = gpos2(i, i), pjj = gpos2(j, j), pij = gpos2(i, j);
    const float Gii = Gh[pii] + Gh[65536 + pii];
    const float Gjj = Gh[pjj] + Gh[65536 + pjj];
    const float Gij = Gh[pij] + Gh[65536 + pij];
    const float d2 = fmaxf(Gii + Gjj - 2.0f * Gij, 0.0f);
    const bool diag = (j == i);
    const float sc = diag ? -3.0e38f : -sqrtf(d2);

    __shared__ float red0[4], red1[4];

    float m = sc;
    #pragma unroll
    for (int off = 32; off; off >>= 1) m = fmaxf(m, __shfl_xor(m, off, 64));
    const int w = j >> 6;
    if ((j & 63) == 0) red0[w] = m;
    __syncthreads();
    m = fmaxf(fmaxf(red0[0], red0[1]), fmaxf(red0[2], red0[3]));

    const float p  = diag ? 0.0f : expf(sc - m);
    const float nm = (labels[j] == labels[i]) ? p : 0.0f;

    float zs = p, ns = nm;
    #pragma unroll
    for (int off = 32; off; off >>= 1) {
        zs += __shfl_xor(zs, off, 64);
        ns += __shfl_xor(ns, off, 64);
    }
    __syncthreads();
    if ((j & 63) == 0) { red0[w] = zs; red1[w] = ns; }
    __syncthreads();
    if (j == 0) {
        const float Z = red0[0] + red0[1] + red0[2] + red0[3];
        const float N = red1[0] + red1[1] + red1[2] + red1[3];
        const float rl = logf(Z) - logf(N);          // >= 0 (N subset of Z)
        const long long q = llrintf(rl * 1048576.0f);
        atomicAdd(acc, (u64t)q);
        __threadfence();
        const u32t c = atomicAdd(cnt, 1u);
        if (c == NROW - 1) {
            __threadfence();
            const u64t tot = atomicAdd(acc, 0ull);
            out[0] = (float)((double)(long long)tot * (1.0 / 1048576.0) * 0.005);
        }
    }
}

extern "C" void kernel_launch(void* const* d_in, const int* in_sizes, int n_in,
                              void* d_out, int out_size, void* d_ws, size_t ws_size,
                              hipStream_t stream) {
    const float* E      = (const float*)d_in[0];
    const int*   labels = (const int*)d_in[1];
    float*       out    = (float*)d_out;

    ushort* part = (ushort*)d_ws;                         // 512 * PSP2 ushorts
    float*  Gh   = (float*)((char*)d_ws + (size_t)512 * PSP2 * sizeof(ushort));
    u64t*   acc  = (u64t*)(Gh + 2 * 65536);
    u32t*   cnt  = (u32t*)(acc + 1);

    gemm_k    <<<512, 512, 0, stream>>>(E, part);
    reduce_k  <<<512, 256, 0, stream>>>(part, Gh, acc, cnt);
    row_loss_k<<<NROW, 256, 0, stream>>>(Gh, labels, acc, cnt, out);
}